// Round 13
// baseline (586.779 us; speedup 1.0000x reference)
//
#include <hip/hip_runtime.h>
#include <hip/hip_bf16.h>

#define NU 262144
#define GG 128
#define PG 134          // padded field side (128 + 2*3)
#define DD 128

typedef __attribute__((ext_vector_type(8))) short short8;   // 8 bf16 MFMA frag
typedef __attribute__((ext_vector_type(4))) float f32x4;

union Frag { short8 s; unsigned u[4]; };

// fp32 -> bf16 RNE (prep kernels)
__device__ __forceinline__ unsigned short f2b(float f) {
  union { float f; unsigned u; } v; v.f = f;
  unsigned r = v.u + 0x7fffu + ((v.u >> 16) & 1u);
  return (unsigned short)(r >> 16);
}
// packed fp32x2 -> bf16x2 (RNE HW instr)
__device__ __forceinline__ unsigned cvtpk(float lo, float hi) {
  unsigned r;
  asm("v_cvt_pk_bf16_f32 %0, %1, %2" : "=v"(r) : "v"(lo), "v"(hi));
  return r;
}

__device__ __forceinline__ float fast_tanh(float x) {
  float ax = fabsf(x);
  float e  = __expf(ax + ax);
  float t  = 1.0f - __fdividef(2.0f, e + 1.0f);
  return copysignf(t, x);
}

// 128 neighborhood offsets = 18 z-rows of 7 + one 2-elem stub (+1 dead row)
struct alignas(16) RowdT { int v[20]; };
static constexpr RowdT mkrowd() {
  RowdT t{};
  for (int r = 0; r < 20; ++r) {
    int rr = (r < 18) ? r : 18;
    int di = (rr < 18) ? (-3 + rr / 7) : -1;
    int dj = (rr < 18) ? (-3 + rr % 7) : 1;
    t.v[r] = (di * PG + dj) * PG - 3;
  }
  return t;
}
__device__ constexpr RowdT ROWD = mkrowd();

// ---------------- prep 1: clamped pad + bf16 field ----------------
__global__ void prep_field(const float* __restrict__ f, unsigned short* __restrict__ fp) {
  int idx = blockIdx.x * 256 + threadIdx.x;
  if (idx >= PG * PG * PG) return;
  int z = idx % PG, t = idx / PG;
  int y = t % PG, x = t / PG;
  int xx = min(max(x - 3, 0), GG - 1);
  int yy = min(max(y - 3, 0), GG - 1);
  int zz = min(max(z - 3, 0), GG - 1);
  fp[idx] = f2b(f[(xx * GG + yy) * GG + zz]);
}

// ---------------- prep 2: weight wall (13 x 8KB) ----------------
__global__ void prep_w(const float* __restrict__ W1, const float* __restrict__ W2,
                       unsigned short* __restrict__ wall) {
  int idx = blockIdx.x * 256 + threadIdx.x;
  if (idx >= 6656) return;
  int kt = idx >> 9, nt = (idx >> 6) & 7, ln = idx & 63;
  int n = nt * 16 + (ln & 15), lg = ln >> 4;
  short8 s;
  if (kt < 4) {
    int k0 = kt * 32 + lg * 8;
#pragma unroll
    for (int j = 0; j < 8; ++j) s[j] = (short)f2b(W1[(k0 + j) * DD + n]);
  } else if (kt < 9) {
    int r = (kt - 4) * 4 + lg;                 // 0..19
#pragma unroll
    for (int j = 0; j < 8; ++j) {
      bool valid = (r < 18 && j < 7) || (r == 18 && j < 2);
      int row = 128 + ((r < 18) ? (r * 7 + j) : (126 + j));
      s[j] = valid ? (short)f2b(W1[row * DD + n]) : (short)0;
    }
  } else {
    int k0 = (kt - 9) * 32 + lg * 8;
#pragma unroll
    for (int j = 0; j < 8; ++j) s[j] = (short)f2b(W2[(k0 + j) * DD + n]);
  }
  ((short8*)wall)[idx] = s;
}

// ---------------- main (ablation-templated): 8 waves/block, wave = 16u x {ev0,ev1} ----
// V=0 full; V=1 NOROW (field rows L1-hot); V=2 NOSIG (sig reads L1-hot);
// V=3 NOPIPE (weights staged once, 1 barrier); V=4 NOTANH.
template<int V>
__global__ __launch_bounds__(512, 4) void atu_main(
    const float* __restrict__ pos, const float* __restrict__ sig,
    const float* __restrict__ offs,
    const float* __restrict__ b1, const float* __restrict__ b2,
    const unsigned short* __restrict__ fpad, const unsigned short* __restrict__ wall,
    float* __restrict__ dbg, float* __restrict__ out_stab, float* __restrict__ out_pos)
{
  constexpr bool NOROW  = (V == 1);
  constexpr bool NOSIG  = (V == 2);
  constexpr bool NOPIPE = (V == 3);
  constexpr bool NOTANH = (V == 4);

  __shared__ unsigned short ldsw[2][8192];   // 2 x 16KB weight buffers
  const int tid  = threadIdx.x;
  const int lane = tid & 63;
  const int lg   = lane >> 4, lm = lane & 15;
  const int wid  = tid >> 6;
  int bid = blockIdx.x;
  int swz = (bid & 7) * 256 + (bid >> 3);      // XCD-bijective (2048 % 8 == 0)
  const int ub = swz * 128 + wid * 16;
  const int un = ub + lm;

  // gather bases: ev0 / ev1
  int abase[2];
  {
    float px = pos[un * 3 + 0], py = pos[un * 3 + 1], pz = pos[un * 3 + 2];
    float qx = px + offs[un * 3 + 0], qy = py + offs[un * 3 + 1], qz = pz + offs[un * 3 + 2];
    int ax = min(max((int)px, 0), GG - 1), ay = min(max((int)py, 0), GG - 1), az = min(max((int)pz, 0), GG - 1);
    int bx = min(max((int)qx, 0), GG - 1), by = min(max((int)qy, 0), GG - 1), bz = min(max((int)qz, 0), GG - 1);
    abase[0] = ((ax + 3) * PG + (ay + 3)) * PG + (az + 3);
    abase[1] = ((bx + 3) * PG + (by + 3)) * PG + (bz + 3);
  }

  const short8* wfr = (const short8*)wall;
  const char* fpadb = (const char*)fpad;

  f32x4 acc[8][2];
#pragma unroll
  for (int nt = 0; nt < 8; ++nt) { acc[nt][0] = f32x4{0.f,0.f,0.f,0.f}; acc[nt][1] = f32x4{0.f,0.f,0.f,0.f}; }
  f32x4 acc2[8][2];
  unsigned Q[2][8][2];

#define WRBUF(H, R0, R1)                                                        \
  if constexpr (!NOPIPE) {                                                      \
    *(short8*)((char*)&ldsw[H][0] + tid * 16) = (R0);                           \
    *(short8*)((char*)&ldsw[H][0] + 8192 + tid * 16) = (R1);                    \
  }

#define BAR() if constexpr (!NOPIPE) __syncthreads();

#define BUFP(KT, HALF) ((const char*)&ldsw[NOPIPE ? 0 : (HALF)][0] + (((KT) & 1) ? 8192 : 0))

#define SIG_KT(KT, HALF)                                                        \
  {                                                                             \
    constexpr int kk = NOSIG ? 0 : (KT);                                        \
    const f32x4* sp = (const f32x4*)(sig + (size_t)un * DD + kk * 32 + lg * 8); \
    f32x4 a = sp[0], b = sp[1];                                                 \
    Frag B;                                                                     \
    B.u[0] = cvtpk(a[0], a[1]); B.u[1] = cvtpk(a[2], a[3]);                     \
    B.u[2] = cvtpk(b[0], b[1]); B.u[3] = cvtpk(b[2], b[3]);                     \
    const char* buf = BUFP(KT, HALF);                                           \
    __builtin_amdgcn_s_setprio(1);                                              \
    _Pragma("unroll")                                                           \
    for (int nt = 0; nt < 8; ++nt) {                                            \
      short8 af = *(const short8*)(buf + (nt * 64 + lane) * 16);                \
      acc[nt][0] = __builtin_amdgcn_mfma_f32_16x16x32_bf16(af, B.s, acc[nt][0], 0, 0, 0); \
    }                                                                           \
    __builtin_amdgcn_s_setprio(0);                                              \
  }

#define ROW_KT(KT, HALF)                                                        \
  {                                                                             \
    int rd = ROWD.v[NOROW ? lg : (((KT) - 4) * 4 + lg)];                        \
    short8 B0 = *(const short8*)(fpadb + 2 * (size_t)(abase[0] + rd));          \
    short8 B1 = *(const short8*)(fpadb + 2 * (size_t)(abase[1] + rd));          \
    const char* buf = BUFP(KT, HALF);                                           \
    __builtin_amdgcn_s_setprio(1);                                              \
    _Pragma("unroll")                                                           \
    for (int nt = 0; nt < 8; ++nt) {                                            \
      short8 af = *(const short8*)(buf + (nt * 64 + lane) * 16);                \
      acc[nt][0] = __builtin_amdgcn_mfma_f32_16x16x32_bf16(af, B0, acc[nt][0], 0, 0, 0); \
      acc[nt][1] = __builtin_amdgcn_mfma_f32_16x16x32_bf16(af, B1, acc[nt][1], 0, 0, 0); \
    }                                                                           \
    __builtin_amdgcn_s_setprio(0);                                              \
  }

#define G2_KT(KT, HALF)                                                         \
  {                                                                             \
    constexpr int kb = (KT) - 9;                                                \
    Frag W[2];                                                                  \
    _Pragma("unroll")                                                           \
    for (int ut = 0; ut < 2; ++ut) {                                            \
      int qa0 = (int)Q[ut][2 * kb][0],     qa1 = (int)Q[ut][2 * kb][1];         \
      int qb0 = (int)Q[ut][2 * kb + 1][0], qb1 = (int)Q[ut][2 * kb + 1][1];     \
      int r00 = __builtin_amdgcn_ds_bpermute(ad0, qa0);                         \
      int r01 = __builtin_amdgcn_ds_bpermute(ad0, qa1);                         \
      int r10 = __builtin_amdgcn_ds_bpermute(ad1, qa0);                         \
      int r11 = __builtin_amdgcn_ds_bpermute(ad1, qa1);                         \
      int s00 = __builtin_amdgcn_ds_bpermute(ad0, qb0);                         \
      int s01 = __builtin_amdgcn_ds_bpermute(ad0, qb1);                         \
      int s10 = __builtin_amdgcn_ds_bpermute(ad1, qb0);                         \
      int s11 = __builtin_amdgcn_ds_bpermute(ad1, qb1);                         \
      W[ut].u[0] = (unsigned)(hi ? s00 : r00);                                  \
      W[ut].u[1] = (unsigned)(hi ? s01 : r01);                                  \
      W[ut].u[2] = (unsigned)(hi ? s10 : r10);                                  \
      W[ut].u[3] = (unsigned)(hi ? s11 : r11);                                  \
    }                                                                           \
    const char* buf = BUFP(KT, HALF);                                           \
    __builtin_amdgcn_s_setprio(1);                                              \
    _Pragma("unroll")                                                           \
    for (int nt = 0; nt < 8; ++nt) {                                            \
      short8 af = *(const short8*)(buf + (nt * 64 + lane) * 16);                \
      acc2[nt][0] = __builtin_amdgcn_mfma_f32_16x16x32_bf16(af, W[0].s, acc2[nt][0], 0, 0, 0); \
      acc2[nt][1] = __builtin_amdgcn_mfma_f32_16x16x32_bf16(af, W[1].s, acc2[nt][1], 0, 0, 0); \
    }                                                                           \
    __builtin_amdgcn_s_setprio(0);                                              \
  }

  const int ad0 = ((((2 * lg) & 3) * 16) + lm) * 4;
  const int ad1 = ((((2 * lg + 1) & 3) * 16) + lm) * 4;
  const bool hi = (lg >= 2);

  // ---- prologue: load pairs 0,1; stage pair0 (always) ----
  short8 c0 = wfr[tid],        c1 = wfr[512 + tid];
  short8 n0, n1;
  if constexpr (!NOPIPE) { n0 = wfr[1024 + tid]; n1 = wfr[1536 + tid]; }
  *(short8*)((char*)&ldsw[0][0] + tid * 16) = c0;
  *(short8*)((char*)&ldsw[0][0] + 8192 + tid * 16) = c1;
  __syncthreads();

  // P0
  if constexpr (!NOPIPE) { c0 = wfr[2048 + tid]; c1 = wfr[2560 + tid]; }
  SIG_KT(0, 0) SIG_KT(1, 0)
  WRBUF(1, n0, n1)
  BAR()

  // P1
  if constexpr (!NOPIPE) { n0 = wfr[3072 + tid]; n1 = wfr[3584 + tid]; }
  SIG_KT(2, 1) SIG_KT(3, 1)
  WRBUF(0, c0, c1)
  BAR()

#pragma unroll
  for (int nt = 0; nt < 8; ++nt) acc[nt][1] = acc[nt][0];

  // P2
  if constexpr (!NOPIPE) { c0 = wfr[4096 + tid]; c1 = wfr[4608 + tid]; }
  ROW_KT(4, 0) ROW_KT(5, 0)
  WRBUF(1, n0, n1)
  BAR()

  // P3
  if constexpr (!NOPIPE) { n0 = wfr[5120 + tid]; n1 = wfr[5632 + tid]; }
  ROW_KT(6, 1) ROW_KT(7, 1)
  WRBUF(0, c0, c1)
  BAR()

  // P4
  if constexpr (!NOPIPE) { c0 = wfr[6144 + tid]; }
  ROW_KT(8, 0)

#pragma unroll
  for (int nt = 0; nt < 8; ++nt) {
    f32x4 b1v = *(const f32x4*)(b1 + nt * 16 + lg * 4);
#pragma unroll
    for (int ut = 0; ut < 2; ++ut) {
      float h0 = NOTANH ? (acc[nt][ut][0] + b1v[0]) : fast_tanh(acc[nt][ut][0] + b1v[0]);
      float h1 = NOTANH ? (acc[nt][ut][1] + b1v[1]) : fast_tanh(acc[nt][ut][1] + b1v[1]);
      float h2 = NOTANH ? (acc[nt][ut][2] + b1v[2]) : fast_tanh(acc[nt][ut][2] + b1v[2]);
      float h3 = NOTANH ? (acc[nt][ut][3] + b1v[3]) : fast_tanh(acc[nt][ut][3] + b1v[3]);
      Q[ut][nt][0] = cvtpk(h0, h1);
      Q[ut][nt][1] = cvtpk(h2, h3);
    }
  }
#pragma unroll
  for (int nt = 0; nt < 8; ++nt) {
    f32x4 b2v = *(const f32x4*)(b2 + nt * 16 + lg * 4);
    acc2[nt][0] = b2v; acc2[nt][1] = b2v;
  }

  G2_KT(9, 0)
  WRBUF(1, n0, n1)
  BAR()

  // P5
  G2_KT(10, 1) G2_KT(11, 1)
  if constexpr (!NOPIPE) *(short8*)((char*)&ldsw[0][0] + tid * 16) = c0;
  BAR()

  // P6
  G2_KT(12, 0)

  // ---- || resp - sig ||^2 ----
  float ssq[2] = {0.f, 0.f};
  f32x4 sv0 = *(const f32x4*)(sig + (size_t)un * DD + lg * 4);   // nt=0 slot
#pragma unroll
  for (int nt = 0; nt < 8; ++nt) {
    f32x4 sv = NOSIG ? sv0 : *(const f32x4*)(sig + (size_t)un * DD + nt * 16 + lg * 4);
#pragma unroll
    for (int ut = 0; ut < 2; ++ut) {
#pragma unroll
      for (int r = 0; r < 4; ++r) {
        float d = acc2[nt][ut][r] - sv[r];
        ssq[ut] = fmaf(d, d, ssq[ut]);
      }
    }
  }
  ssq[0] += __shfl_xor(ssq[0], 16, 64); ssq[0] += __shfl_xor(ssq[0], 32, 64);
  ssq[1] += __shfl_xor(ssq[1], 16, 64); ssq[1] += __shfl_xor(ssq[1], 32, 64);

  if (lane < 16) {
    if (dbg) dbg[un] = ssq[0] + ssq[1];           // keepalive for ablation variants
    if (out_stab) {
      float px = pos[un * 3 + 0], py = pos[un * 3 + 1], pz = pos[un * 3 + 2];
      float ox = offs[un * 3 + 0], oy = offs[un * 3 + 1], oz = offs[un * 3 + 2];
      bool ok = ssq[1] <= ssq[0];
      out_stab[un] = sqrtf(ok ? ssq[1] : ssq[0]);
      out_pos[un * 3 + 0] = ok ? px + ox : px;
      out_pos[un * 3 + 1] = ok ? py + oy : py;
      out_pos[un * 3 + 2] = ok ? pz + oz : pz;
    }
  }
#undef WRBUF
#undef BAR
#undef BUFP
#undef SIG_KT
#undef ROW_KT
#undef G2_KT
}

extern "C" void kernel_launch(void* const* d_in, const int* in_sizes, int n_in,
                              void* d_out, int out_size, void* d_ws, size_t ws_size,
                              hipStream_t stream) {
  const float* field = (const float*)d_in[0];
  const float* pos   = (const float*)d_in[1];
  const float* sig   = (const float*)d_in[2];
  const float* offs  = (const float*)d_in[3];
  const float* W1    = (const float*)d_in[4];
  const float* b1    = (const float*)d_in[5];
  const float* W2    = (const float*)d_in[6];
  const float* b2    = (const float*)d_in[7];
  float* out_stab = (float*)d_out;
  float* out_pos  = out_stab + NU;

  char* ws = (char*)d_ws;
  unsigned short* fpad = (unsigned short*)ws;                 // 4,812,208 B (+slack)
  unsigned short* wall = (unsigned short*)(ws + 4812800);     // 106,496 B (13 x 8KB)
  float* dbg = (float*)(ws + 4919296);                        // 5 x 1MB ablation sinks
  const size_t need_abl = 4919296ull + 5ull * NU * 4ull;

  prep_field<<<(PG * PG * PG + 255) / 256, 256, 0, stream>>>(field, fpad);
  prep_w<<<26, 256, 0, stream>>>(W1, W2, wall);

  if (ws_size >= need_abl) {
    // Ablation dispatches (order: V1 NOROW, V2 NOSIG, V3 NOPIPE, V4 NOTANH) -> scratch
    atu_main<1><<<NU / 128, 512, 0, stream>>>(pos, sig, offs, b1, b2, fpad, wall,
                                              dbg + 1 * NU, nullptr, nullptr);
    atu_main<2><<<NU / 128, 512, 0, stream>>>(pos, sig, offs, b1, b2, fpad, wall,
                                              dbg + 2 * NU, nullptr, nullptr);
    atu_main<3><<<NU / 128, 512, 0, stream>>>(pos, sig, offs, b1, b2, fpad, wall,
                                              dbg + 3 * NU, nullptr, nullptr);
    atu_main<4><<<NU / 128, 512, 0, stream>>>(pos, sig, offs, b1, b2, fpad, wall,
                                              dbg + 4 * NU, nullptr, nullptr);
    // Real run (V0) -> outputs
    atu_main<0><<<NU / 128, 512, 0, stream>>>(pos, sig, offs, b1, b2, fpad, wall,
                                              dbg, out_stab, out_pos);
  } else {
    atu_main<0><<<NU / 128, 512, 0, stream>>>(pos, sig, offs, b1, b2, fpad, wall,
                                              nullptr, out_stab, out_pos);
  }
}

// Round 14
// 160.156 us; speedup vs baseline: 3.6638x; 3.6638x over previous
//
#include <hip/hip_runtime.h>
#include <hip/hip_bf16.h>

#define NU 262144
#define GG 128
#define PG 134          // padded field side (128 + 2*3)
#define DD 128

typedef __attribute__((ext_vector_type(8))) short short8;   // 8 bf16 MFMA frag
typedef __attribute__((ext_vector_type(4))) float f32x4;

union Frag { short8 s; unsigned u[4]; };

// fp32 -> bf16 RNE (prep kernels)
__device__ __forceinline__ unsigned short f2b(float f) {
  union { float f; unsigned u; } v; v.f = f;
  unsigned r = v.u + 0x7fffu + ((v.u >> 16) & 1u);
  return (unsigned short)(r >> 16);
}
// packed fp32x2 -> bf16x2 (RNE HW instr)
__device__ __forceinline__ unsigned cvtpk(float lo, float hi) {
  unsigned r;
  asm("v_cvt_pk_bf16_f32 %0, %1, %2" : "=v"(r) : "v"(lo), "v"(hi));
  return r;
}

__device__ __forceinline__ float fast_tanh(float x) {
  float ax = fabsf(x);
  float e  = __expf(ax + ax);
  float t  = 1.0f - __fdividef(2.0f, e + 1.0f);
  return copysignf(t, x);
}

// 128 neighborhood offsets = 18 z-rows of 7 + one 2-elem stub (+1 dead row)
struct alignas(16) RowdT { int v[20]; };
static constexpr RowdT mkrowd() {
  RowdT t{};
  for (int r = 0; r < 20; ++r) {
    int rr = (r < 18) ? r : 18;
    int di = (rr < 18) ? (-3 + rr / 7) : -1;
    int dj = (rr < 18) ? (-3 + rr % 7) : 1;
    t.v[r] = (di * PG + dj) * PG - 3;
  }
  return t;
}
__device__ constexpr RowdT ROWD = mkrowd();

// ---------------- prep 1: clamped pad + bf16 field ----------------
__global__ void prep_field(const float* __restrict__ f, unsigned short* __restrict__ fp) {
  int idx = blockIdx.x * 256 + threadIdx.x;
  if (idx >= PG * PG * PG) return;
  int z = idx % PG, t = idx / PG;
  int y = t % PG, x = t / PG;
  int xx = min(max(x - 3, 0), GG - 1);
  int yy = min(max(y - 3, 0), GG - 1);
  int zz = min(max(z - 3, 0), GG - 1);
  fp[idx] = f2b(f[(xx * GG + yy) * GG + zz]);
}

// ---------------- prep 2: weight wall (13 x 8KB) ----------------
// kt 0-3: W1 sig half; kt 4-8: W1 gather rows (reordered, zero-padded); kt 9-12: W2.
__global__ void prep_w(const float* __restrict__ W1, const float* __restrict__ W2,
                       unsigned short* __restrict__ wall) {
  int idx = blockIdx.x * 256 + threadIdx.x;
  if (idx >= 6656) return;
  int kt = idx >> 9, nt = (idx >> 6) & 7, ln = idx & 63;
  int n = nt * 16 + (ln & 15), lg = ln >> 4;
  short8 s;
  if (kt < 4) {
    int k0 = kt * 32 + lg * 8;
#pragma unroll
    for (int j = 0; j < 8; ++j) s[j] = (short)f2b(W1[(k0 + j) * DD + n]);
  } else if (kt < 9) {
    int r = (kt - 4) * 4 + lg;                 // 0..19
#pragma unroll
    for (int j = 0; j < 8; ++j) {
      bool valid = (r < 18 && j < 7) || (r == 18 && j < 2);
      int row = 128 + ((r < 18) ? (r * 7 + j) : (126 + j));
      s[j] = valid ? (short)f2b(W1[row * DD + n]) : (short)0;
    }
  } else {
    int k0 = (kt - 9) * 32 + lg * 8;
#pragma unroll
    for (int j = 0; j < 8; ++j) s[j] = (short)f2b(W2[(k0 + j) * DD + n]);
  }
  ((short8*)wall)[idx] = s;
}

// ---------------- main: 8 waves/block, wave = 32 units x {ev0, ev1} = 64 cols ----------------
// One-shot 72KB LDS weight stage (GEMM1), restage W2 over first 32KB for GEMM2.
// 3 barriers. Each weight ds_read feeds 4 MFMAs (sets: ug0ev0, ug1ev0, ug0ev1, ug1ev1).
__global__ __launch_bounds__(512, 2) void atu_main(
    const float* __restrict__ pos, const float* __restrict__ sig,
    const float* __restrict__ offs,
    const float* __restrict__ b1, const float* __restrict__ b2,
    const unsigned short* __restrict__ fpad, const unsigned short* __restrict__ wall,
    float* __restrict__ out_stab, float* __restrict__ out_pos)
{
  __shared__ unsigned short ldsw[9 * 4096];    // 72 KB
  const int tid  = threadIdx.x;
  const int lane = tid & 63;
  const int lg   = lane >> 4, lm = lane & 15;
  const int wid  = tid >> 6;
  int bid = blockIdx.x;
  int swz = (bid & 7) * 128 + (bid >> 3);      // 1024 blocks, XCD-bijective
  const int ub  = swz * 256 + wid * 32;        // 32 units per wave
  const int un0 = ub + lm, un1 = ub + 16 + lm;

  short8* lds8 = (short8*)ldsw;
  const short8* wfr = (const short8*)wall;

  // ---- one-shot stage of all 9 GEMM1 kt-blocks ----
#pragma unroll
  for (int i = 0; i < 9; ++i) lds8[i * 512 + tid] = wfr[i * 512 + tid];

  // ---- gather bases: s = 0:ug0ev0, 1:ug1ev0, 2:ug0ev1, 3:ug1ev1 ----
  int abase[4];
#pragma unroll
  for (int ug = 0; ug < 2; ++ug) {
    int u = ub + ug * 16 + lm;
    float px = pos[u * 3 + 0], py = pos[u * 3 + 1], pz = pos[u * 3 + 2];
    float qx = px + offs[u * 3 + 0], qy = py + offs[u * 3 + 1], qz = pz + offs[u * 3 + 2];
    int ax = min(max((int)px, 0), GG - 1), ay = min(max((int)py, 0), GG - 1), az = min(max((int)pz, 0), GG - 1);
    int bx = min(max((int)qx, 0), GG - 1), by = min(max((int)qy, 0), GG - 1), bz = min(max((int)qz, 0), GG - 1);
    abase[ug]     = ((ax + 3) * PG + (ay + 3)) * PG + (az + 3);
    abase[2 + ug] = ((bx + 3) * PG + (by + 3)) * PG + (bz + 3);
  }
  __syncthreads();

  f32x4 acc[8][4];
#pragma unroll
  for (int nt = 0; nt < 8; ++nt)
#pragma unroll
    for (int s = 0; s < 4; ++s) acc[nt][s] = f32x4{0.f, 0.f, 0.f, 0.f};

  // ---- GEMM1 sig kts 0-3 (ev-shared: accumulate into sets 0,1 only) ----
#pragma unroll
  for (int kt = 0; kt < 4; ++kt) {
    Frag B[2];
#pragma unroll
    for (int ug = 0; ug < 2; ++ug) {
      const f32x4* sp = (const f32x4*)(sig + (size_t)(ub + ug * 16 + lm) * DD + kt * 32 + lg * 8);
      f32x4 a = sp[0], b = sp[1];
      B[ug].u[0] = cvtpk(a[0], a[1]); B[ug].u[1] = cvtpk(a[2], a[3]);
      B[ug].u[2] = cvtpk(b[0], b[1]); B[ug].u[3] = cvtpk(b[2], b[3]);
    }
    const char* buf = (const char*)ldsw + kt * 8192;
#pragma unroll
    for (int nt = 0; nt < 8; ++nt) {
      short8 af = *(const short8*)(buf + (nt * 64 + lane) * 16);
      acc[nt][0] = __builtin_amdgcn_mfma_f32_16x16x32_bf16(af, B[0].s, acc[nt][0], 0, 0, 0);
      acc[nt][1] = __builtin_amdgcn_mfma_f32_16x16x32_bf16(af, B[1].s, acc[nt][1], 0, 0, 0);
    }
  }
#pragma unroll
  for (int nt = 0; nt < 8; ++nt) { acc[nt][2] = acc[nt][0]; acc[nt][3] = acc[nt][1]; }

  // ---- GEMM1 row kts 4-8 (per-set gathers; each weight read feeds 4 MFMAs) ----
  const char* fpadb = (const char*)fpad;
#pragma unroll
  for (int kt = 4; kt < 9; ++kt) {
    int rd = ROWD.v[(kt - 4) * 4 + lg];
    short8 B[4];
#pragma unroll
    for (int s = 0; s < 4; ++s)
      B[s] = *(const short8*)(fpadb + 2 * (size_t)(abase[s] + rd));
    const char* buf = (const char*)ldsw + kt * 8192;
#pragma unroll
    for (int nt = 0; nt < 8; ++nt) {
      short8 af = *(const short8*)(buf + (nt * 64 + lane) * 16);
#pragma unroll
      for (int s = 0; s < 4; ++s)
        acc[nt][s] = __builtin_amdgcn_mfma_f32_16x16x32_bf16(af, B[s], acc[nt][s], 0, 0, 0);
    }
  }

  // ---- bias + tanh + pack + in-register transpose -> Wt[s][kb] (once) ----
  const int ad0 = ((((2 * lg) & 3) * 16) + lm) * 4;
  const int ad1 = ((((2 * lg + 1) & 3) * 16) + lm) * 4;
  const bool hi = (lg >= 2);
  Frag Wt[4][4];
#pragma unroll
  for (int kb = 0; kb < 4; ++kb) {
    f32x4 b1a = *(const f32x4*)(b1 + (2 * kb) * 16 + lg * 4);
    f32x4 b1b = *(const f32x4*)(b1 + (2 * kb + 1) * 16 + lg * 4);
#pragma unroll
    for (int s = 0; s < 4; ++s) {
      float a0 = fast_tanh(acc[2 * kb][s][0] + b1a[0]);
      float a1 = fast_tanh(acc[2 * kb][s][1] + b1a[1]);
      float a2 = fast_tanh(acc[2 * kb][s][2] + b1a[2]);
      float a3 = fast_tanh(acc[2 * kb][s][3] + b1a[3]);
      float c0 = fast_tanh(acc[2 * kb + 1][s][0] + b1b[0]);
      float c1 = fast_tanh(acc[2 * kb + 1][s][1] + b1b[1]);
      float c2 = fast_tanh(acc[2 * kb + 1][s][2] + b1b[2]);
      float c3 = fast_tanh(acc[2 * kb + 1][s][3] + b1b[3]);
      int qa0 = (int)cvtpk(a0, a1), qa1 = (int)cvtpk(a2, a3);
      int qb0 = (int)cvtpk(c0, c1), qb1 = (int)cvtpk(c2, c3);
      int r00 = __builtin_amdgcn_ds_bpermute(ad0, qa0);
      int r01 = __builtin_amdgcn_ds_bpermute(ad0, qa1);
      int r10 = __builtin_amdgcn_ds_bpermute(ad1, qa0);
      int r11 = __builtin_amdgcn_ds_bpermute(ad1, qa1);
      int s00 = __builtin_amdgcn_ds_bpermute(ad0, qb0);
      int s01 = __builtin_amdgcn_ds_bpermute(ad0, qb1);
      int s10 = __builtin_amdgcn_ds_bpermute(ad1, qb0);
      int s11 = __builtin_amdgcn_ds_bpermute(ad1, qb1);
      Wt[s][kb].u[0] = (unsigned)(hi ? s00 : r00);
      Wt[s][kb].u[1] = (unsigned)(hi ? s01 : r01);
      Wt[s][kb].u[2] = (unsigned)(hi ? s10 : r10);
      Wt[s][kb].u[3] = (unsigned)(hi ? s11 : r11);
    }
  }

  // ---- restage W2 (kts 9-12) over first 32KB ----
  __syncthreads();
#pragma unroll
  for (int i = 0; i < 4; ++i) lds8[i * 512 + tid] = wfr[(9 + i) * 512 + tid];
  __syncthreads();

  // ---- GEMM2 in two nt-halves (acc2[4][4]) + fused norm ----
  float ssq[4] = {0.f, 0.f, 0.f, 0.f};
#pragma unroll 1
  for (int half = 0; half < 2; ++half) {
    f32x4 acc2[4][4];
#pragma unroll
    for (int n2 = 0; n2 < 4; ++n2) {
      f32x4 b2v = *(const f32x4*)(b2 + (half * 4 + n2) * 16 + lg * 4);
#pragma unroll
      for (int s = 0; s < 4; ++s) acc2[n2][s] = b2v;
    }
#pragma unroll
    for (int kt = 0; kt < 4; ++kt) {
      const char* buf = (const char*)ldsw + kt * 8192;
#pragma unroll
      for (int n2 = 0; n2 < 4; ++n2) {
        int nt = half * 4 + n2;
        short8 af = *(const short8*)(buf + (nt * 64 + lane) * 16);
#pragma unroll
        for (int s = 0; s < 4; ++s)
          acc2[n2][s] = __builtin_amdgcn_mfma_f32_16x16x32_bf16(af, Wt[s][kt].s, acc2[n2][s], 0, 0, 0);
      }
    }
    // norm partials for this half
#pragma unroll
    for (int n2 = 0; n2 < 4; ++n2) {
      int nt = half * 4 + n2;
      f32x4 sv0 = *(const f32x4*)(sig + (size_t)un0 * DD + nt * 16 + lg * 4);
      f32x4 sv1 = *(const f32x4*)(sig + (size_t)un1 * DD + nt * 16 + lg * 4);
#pragma unroll
      for (int s = 0; s < 4; ++s) {
        f32x4 sv = (s & 1) ? sv1 : sv0;
#pragma unroll
        for (int r = 0; r < 4; ++r) {
          float d = acc2[n2][s][r] - sv[r];
          ssq[s] = fmaf(d, d, ssq[s]);
        }
      }
    }
  }

#pragma unroll
  for (int s = 0; s < 4; ++s) {
    ssq[s] += __shfl_xor(ssq[s], 16, 64);
    ssq[s] += __shfl_xor(ssq[s], 32, 64);
  }

  // ---- accept / outputs: lanes 0-15 -> ug0 units, lanes 16-31 -> ug1 units ----
  if (lane < 32) {
    bool g1 = (lane >= 16);
    float e0 = g1 ? ssq[1] : ssq[0];
    float e1 = g1 ? ssq[3] : ssq[2];
    int un = ub + (lane & 31);
    float px = pos[un * 3 + 0], py = pos[un * 3 + 1], pz = pos[un * 3 + 2];
    float ox = offs[un * 3 + 0], oy = offs[un * 3 + 1], oz = offs[un * 3 + 2];
    bool ok = e1 <= e0;
    out_stab[un] = sqrtf(ok ? e1 : e0);
    out_pos[un * 3 + 0] = ok ? px + ox : px;
    out_pos[un * 3 + 1] = ok ? py + oy : py;
    out_pos[un * 3 + 2] = ok ? pz + oz : pz;
  }
}

extern "C" void kernel_launch(void* const* d_in, const int* in_sizes, int n_in,
                              void* d_out, int out_size, void* d_ws, size_t ws_size,
                              hipStream_t stream) {
  const float* field = (const float*)d_in[0];
  const float* pos   = (const float*)d_in[1];
  const float* sig   = (const float*)d_in[2];
  const float* offs  = (const float*)d_in[3];
  const float* W1    = (const float*)d_in[4];
  const float* b1    = (const float*)d_in[5];
  const float* W2    = (const float*)d_in[6];
  const float* b2    = (const float*)d_in[7];
  float* out_stab = (float*)d_out;
  float* out_pos  = out_stab + NU;

  char* ws = (char*)d_ws;
  unsigned short* fpad = (unsigned short*)ws;                 // 4,812,208 B (+slack)
  unsigned short* wall = (unsigned short*)(ws + 4812800);     // 106,496 B (13 x 8KB)

  prep_field<<<(PG * PG * PG + 255) / 256, 256, 0, stream>>>(field, fpad);
  prep_w<<<26, 256, 0, stream>>>(W1, W2, wall);
  atu_main<<<NU / 256, 512, 0, stream>>>(pos, sig, offs, b1, b2,
                                         fpad, wall, out_stab, out_pos);
}